// Round 6
// baseline (229.751 us; speedup 1.0000x reference)
//
#include <hip/hip_runtime.h>
#include <hip/hip_bf16.h>
#include <math.h>

#define BB 8
#define NN 512
#define DD 256
#define BNT 4096   // B*N

typedef __attribute__((ext_vector_type(8))) short short8;
typedef __attribute__((ext_vector_type(4))) float f32x4;

// Workspace layout (float offsets). Total ~20.3 MB (masks never materialized).
#define OFF_S0    0u          // fp32 [4096][256]   s0
#define OFF_S0T   1048576u    // bf16 [8][256][512] s0 transposed per batch
#define OFF_SA    1572864u    // bf16 [4096][1536]  aggregated S (r-major cols)
#define OFF_CNT   4718592u    // int  [4096][8]     relation counts per (b,j)
#define OFF_WCT   4751360u    // bf16 [256][1536]   Wcat^T  (e rows, k=(r,d))
#define OFF_WBT   4947968u    // bf16 [1024][256]   Wbig^T  (c rows, k=d)
#define OFF_BB    5079040u    // fp32 [1024]        h1b|outb

// d_out layout (floats)
#define OUT0_OFF   0u        // output  [8][512][256]
#define INTERP_OFF 1048576u  // interp  [3][4096]
#define SYM_OFF    1060864u  // symbols [8][512][256]

__device__ __forceinline__ float gelu_exact(float x) {
    return 0.5f * x * (1.0f + erff(x * 0.70710678118654752f));
}

__device__ __forceinline__ ushort f2bf(float x) {
    __hip_bfloat16 h = __float2bfloat16(x);
    union { __hip_bfloat16 b; ushort u; } cv;
    cv.b = h;
    return cv.u;
}

__device__ __forceinline__ int rel_of(float dx, float dy) {
    if (dy >  0.5f) return 0;
    if (dy < -0.5f) return 1;
    if (dx < -0.5f) return 2;
    if (dx >  0.5f) return 3;
    if (fabsf(dx) < 0.3f && fabsf(dy) < 0.3f) return 4;
    return 5;
}

// ================= shared MFMA core: 128x128 tile, BK=32, 4 waves 2x2 =====
// A [M][K] row-major bf16 (k-contiguous), B stored transposed [N][K] bf16.
// LDS: 16B chunks [quad(k/8)][row]. Fragments (verified m89/m91/m120):
// A: m=lane&15,k=quad*8+j; B: n=lane&15; C/D: col=lane&15,row=quad*4+reg.
__device__ __forceinline__ void gemm_core(
    const ushort* __restrict__ Ag, int lda,
    const ushort* __restrict__ Bg, int ldb, int K,
    int row0, int col0, int tid,
    ushort* Als, ushort* Bls, f32x4 acc[4][4])
{
    const int lane = tid & 63, w = tid >> 6;
    const int wm = w >> 1, wn = w & 1;
    const int quad = lane >> 4, l15 = lane & 15;
    const int sm = tid >> 1;
    const int sq = (tid & 1) * 2;
    const ushort* gA = Ag + (size_t)(row0 + sm) * lda + sq * 8;
    const ushort* gB = Bg + (size_t)(col0 + sm) * ldb + sq * 8;

    for (int k0 = 0; k0 < K; k0 += 32) {
        uint4 a0 = *(const uint4*)(gA + k0);
        uint4 a1 = *(const uint4*)(gA + k0 + 8);
        uint4 b0 = *(const uint4*)(gB + k0);
        uint4 b1 = *(const uint4*)(gB + k0 + 8);
        __syncthreads();
        *(uint4*)&Als[(sq * 128 + sm) * 8]       = a0;
        *(uint4*)&Als[((sq + 1) * 128 + sm) * 8] = a1;
        *(uint4*)&Bls[(sq * 128 + sm) * 8]       = b0;
        *(uint4*)&Bls[((sq + 1) * 128 + sm) * 8] = b1;
        __syncthreads();
        short8 af[4], bf[4];
#pragma unroll
        for (int mt = 0; mt < 4; mt++)
            af[mt] = *(const short8*)&Als[(quad * 128 + wm * 64 + mt * 16 + l15) * 8];
#pragma unroll
        for (int nt = 0; nt < 4; nt++)
            bf[nt] = *(const short8*)&Bls[(quad * 128 + wn * 64 + nt * 16 + l15) * 8];
#pragma unroll
        for (int mt = 0; mt < 4; mt++)
#pragma unroll
            for (int nt = 0; nt < 4; nt++)
                acc[mt][nt] = __builtin_amdgcn_mfma_f32_16x16x32_bf16(
                    af[mt], bf[nt], acc[mt][nt], 0, 0, 0);
    }
}

// Same core but A is fp32 in global memory, converted to bf16 at staging.
__device__ __forceinline__ void gemm_core_f32A(
    const float* __restrict__ Ag, int lda,
    const ushort* __restrict__ Bg, int ldb, int K,
    int row0, int col0, int tid,
    ushort* Als, ushort* Bls, f32x4 acc[4][4])
{
    const int lane = tid & 63, w = tid >> 6;
    const int wm = w >> 1, wn = w & 1;
    const int quad = lane >> 4, l15 = lane & 15;
    const int sm = tid >> 1;
    const int sq = (tid & 1) * 2;
    const float*  gA = Ag + (size_t)(row0 + sm) * lda + sq * 8;
    const ushort* gB = Bg + (size_t)(col0 + sm) * ldb + sq * 8;

    for (int k0 = 0; k0 < K; k0 += 32) {
        union alignas(16) { float f[16]; float4 v4[4]; } af32;
        af32.v4[0] = *(const float4*)(gA + k0);
        af32.v4[1] = *(const float4*)(gA + k0 + 4);
        af32.v4[2] = *(const float4*)(gA + k0 + 8);
        af32.v4[3] = *(const float4*)(gA + k0 + 12);
        uint4 b0 = *(const uint4*)(gB + k0);
        uint4 b1 = *(const uint4*)(gB + k0 + 8);
        union alignas(16) { ushort u[16]; uint4 v[2]; } am;
#pragma unroll
        for (int t = 0; t < 16; t++) am.u[t] = f2bf(af32.f[t]);
        __syncthreads();
        *(uint4*)&Als[(sq * 128 + sm) * 8]       = am.v[0];
        *(uint4*)&Als[((sq + 1) * 128 + sm) * 8] = am.v[1];
        *(uint4*)&Bls[(sq * 128 + sm) * 8]       = b0;
        *(uint4*)&Bls[((sq + 1) * 128 + sm) * 8] = b1;
        __syncthreads();
        short8 af[4], bf[4];
#pragma unroll
        for (int mt = 0; mt < 4; mt++)
            af[mt] = *(const short8*)&Als[(quad * 128 + wm * 64 + mt * 16 + l15) * 8];
#pragma unroll
        for (int nt = 0; nt < 4; nt++)
            bf[nt] = *(const short8*)&Bls[(quad * 128 + wn * 64 + nt * 16 + l15) * 8];
#pragma unroll
        for (int mt = 0; mt < 4; mt++)
#pragma unroll
            for (int nt = 0; nt < 4; nt++)
                acc[mt][nt] = __builtin_amdgcn_mfma_f32_16x16x32_bf16(
                    af[mt], bf[nt], acc[mt][nt], 0, 0, 0);
    }
}

#define GEMM_PROLOGUE()                                        \
    __shared__ ushort Als[4096], Bls[4096];                    \
    int tid = threadIdx.x;                                     \
    f32x4 acc[4][4];                                           \
    _Pragma("unroll") for (int mt = 0; mt < 4; mt++)           \
    _Pragma("unroll") for (int nt = 0; nt < 4; nt++)           \
        acc[mt][nt] = (f32x4){0.f, 0.f, 0.f, 0.f};

#define EPI_IDS()                                              \
    int lane = tid & 63, w = tid >> 6;                         \
    int wm = w >> 1, wn = w & 1;                               \
    int quad = lane >> 4, l15 = lane & 15;

// ---------------------------------------------------------------- prep ----
__global__ __launch_bounds__(256) void prep_kernel(
    const float* __restrict__ relW, const float* __restrict__ h1W,
    const float* __restrict__ outW, const float* __restrict__ h1b,
    const float* __restrict__ outb,
    ushort* __restrict__ WcT, ushort* __restrict__ WbT,
    float* __restrict__ bbig)
{
    int idx = blockIdx.x * 256 + threadIdx.x;    // grid 1536 -> 393216
    {
        int e = idx / 1536, k = idx - e * 1536;
        int r = k >> 8, d = k & 255;
        WcT[idx] = f2bf(relW[(r * DD + d) * DD + e]);
    }
    if (idx < 262144) {
        int c = idx >> 8, d = idx & 255;
        float v;
        if (c < 768) { int r = c >> 8, e = c & 255; v = h1W[(r * DD + d) * DD + e]; }
        else         { v = outW[d * DD + (c - 768)]; }
        WbT[idx] = f2bf(v);
    }
    if (idx < 1024) bbig[idx] = (idx < 768) ? h1b[idx] : outb[idx - 768];
}

// -------------------------------------------------------------- gather ----
__global__ __launch_bounds__(256) void gather_kernel(
    const int* __restrict__ ids, const float* __restrict__ symt,
    const float* __restrict__ layt, float* __restrict__ s0)
{
    int idx = blockIdx.x * 256 + threadIdx.x;   // 1048576
    int row = idx >> 8, c = idx & 255;
    int id = ids[row];
    s0[idx] = symt[id * DD + c] + layt[id * DD + c];
}

// ----------------------------------------------------------- transpose ----
__global__ __launch_bounds__(256) void transpose_kernel(
    const float* __restrict__ s0, ushort* __restrict__ s0T)
{
    __shared__ float tile[64][65];
    int b = blockIdx.z, i0 = blockIdx.x * 64, d0 = blockIdx.y * 64;
    int x = threadIdx.x & 63, g = threadIdx.x >> 6;
#pragma unroll
    for (int k = 0; k < 16; k++) {
        int il = g * 16 + k;
        tile[il][x] = s0[((size_t)(b * NN) + i0 + il) * DD + d0 + x];
    }
    __syncthreads();
#pragma unroll
    for (int k = 0; k < 16; k++) {
        int dl = g * 16 + k;
        s0T[((size_t)(b * DD) + d0 + dl) * NN + i0 + x] = f2bf(tile[x][dl]);
    }
}

// --------------------------------------------------------------- counts ---
// cnt[b*512+j][r] = #{i != j : rel(i,j)=r}; no mask materialization.
__global__ __launch_bounds__(256) void count_kernel(
    const float* __restrict__ positions, int* __restrict__ cnt)
{
    int b = blockIdx.x >> 3;
    int jt = blockIdx.x & 7;
    int tid = threadIdx.x, lane = tid & 63, w = tid >> 6;
    __shared__ float px[NN], py[NN];
    for (int i = tid; i < NN; i += 256) {
        float2 p = ((const float2*)positions)[b * NN + i];
        px[i] = p.x; py[i] = p.y;
    }
    __syncthreads();
    for (int jj = 0; jj < 16; jj++) {
        int j = jt * 64 + w * 16 + jj;
        float xj = px[j], yj = py[j];
        int c[6] = {0, 0, 0, 0, 0, 0};
        for (int it = 0; it < 8; it++) {
            int i = it * 64 + lane;
            int r = rel_of(xj - px[i], yj - py[i]);
            if (i == j) r = 6;
#pragma unroll
            for (int rr = 0; rr < 6; rr++) c[rr] += (r == rr) ? 1 : 0;
        }
#pragma unroll
        for (int rr = 0; rr < 6; rr++) {
            int v = c[rr];
            v += __shfl_xor(v, 32); v += __shfl_xor(v, 16);
            v += __shfl_xor(v, 8);  v += __shfl_xor(v, 4);
            v += __shfl_xor(v, 2);  v += __shfl_xor(v, 1);
            if (lane == 0) cnt[(b * NN + j) * 8 + rr] = v;
        }
    }
}

// ------------------------------------------------------------ init sym ----
// symOut = s0 + sum_r cnt_r * relb_r  (base for gemm1's atomic partial sums)
__global__ __launch_bounds__(256) void init_sym_kernel(
    const float* __restrict__ s0, const int* __restrict__ cnt,
    const float* __restrict__ relb, float* __restrict__ symOut)
{
    int idx = blockIdx.x * 256 + threadIdx.x;   // 1048576
    int row = idx >> 8, e = idx & 255;
    float v = s0[idx];
#pragma unroll
    for (int rr = 0; rr < 6; rr++)
        v += (float)cnt[row * 8 + rr] * relb[rr * DD + e];
    symOut[idx] = v;
}

// ---------------------------------------------------------- init interp ---
__global__ __launch_bounds__(256) void init_interp_kernel(
    const float* __restrict__ h2b, float* __restrict__ outI)
{
    int idx = blockIdx.x * 256 + threadIdx.x;   // 12288
    if (idx < 3 * BNT) outI[idx] = h2b[idx >> 12];
}

// ------------------------------------------------------------- agg gemm ---
// SA[b*512+j][r*256+d] = sum_i 1[rel(i,j)=r, i!=j] * s0[b][i][d].
// The one-hot A-tile is GENERATED from positions during staging (no mask
// buffer). B = s0T (bf16, [d][i]).
__global__ __launch_bounds__(256) void agg_gemm(
    const float* __restrict__ positions, const ushort* __restrict__ s0T,
    ushort* __restrict__ SA)
{
    GEMM_PROLOGUE();
    __shared__ float px[NN], py[NN];
    int z = blockIdx.z, b = z / 6, r = z - b * 6;
    int row0 = blockIdx.y * 128, col0 = blockIdx.x * 128;
    for (int i = tid; i < NN; i += 256) {
        float2 p = ((const float2*)positions)[b * NN + i];
        px[i] = p.x; py[i] = p.y;
    }
    const int lane = tid & 63, w = tid >> 6;
    const int wm = w >> 1, wn = w & 1;
    const int quad = lane >> 4, l15 = lane & 15;
    const int sm = tid >> 1;
    const int sq = (tid & 1) * 2;
    const int j = row0 + sm;
    const ushort* gB = s0T + (size_t)b * DD * NN + (size_t)(col0 + sm) * NN + sq * 8;
    __syncthreads();
    const float xj = px[j], yj = py[j];

    for (int k0 = 0; k0 < NN; k0 += 32) {
        uint4 b0 = *(const uint4*)(gB + k0);
        uint4 b1 = *(const uint4*)(gB + k0 + 8);
        union alignas(16) { ushort u[16]; uint4 v[2]; } am;
#pragma unroll
        for (int t = 0; t < 16; t++) {
            int i = k0 + sq * 8 + t;
            int rr = rel_of(xj - px[i], yj - py[i]);
            am.u[t] = (rr == r && i != j) ? 0x3F80 : 0;
        }
        __syncthreads();
        *(uint4*)&Als[(sq * 128 + sm) * 8]       = am.v[0];
        *(uint4*)&Als[((sq + 1) * 128 + sm) * 8] = am.v[1];
        *(uint4*)&Bls[(sq * 128 + sm) * 8]       = b0;
        *(uint4*)&Bls[((sq + 1) * 128 + sm) * 8] = b1;
        __syncthreads();
        short8 af[4], bf[4];
#pragma unroll
        for (int mt = 0; mt < 4; mt++)
            af[mt] = *(const short8*)&Als[(quad * 128 + wm * 64 + mt * 16 + l15) * 8];
#pragma unroll
        for (int nt = 0; nt < 4; nt++)
            bf[nt] = *(const short8*)&Bls[(quad * 128 + wn * 64 + nt * 16 + l15) * 8];
#pragma unroll
        for (int mt = 0; mt < 4; mt++)
#pragma unroll
            for (int nt = 0; nt < 4; nt++)
                acc[mt][nt] = __builtin_amdgcn_mfma_f32_16x16x32_bf16(
                    af[mt], bf[nt], acc[mt][nt], 0, 0, 0);
    }
#pragma unroll
    for (int mt = 0; mt < 4; mt++)
#pragma unroll
        for (int nt = 0; nt < 4; nt++)
#pragma unroll
            for (int v = 0; v < 4; v++) {
                int row = row0 + wm * 64 + mt * 16 + quad * 4 + v;
                int col = col0 + wn * 64 + nt * 16 + l15;
                SA[(size_t)(b * NN + row) * 1536 + r * DD + col] =
                    f2bf(acc[mt][nt][v]);
            }
}

// ----------------------------------------------------------------- gemm1 --
// Split-K over r: grid (2, 32, 6). Each slice computes
// SA[:, r*256:(r+1)*256] @ Wcat-slice and atomicAdds into symOut
// (pre-initialized by init_sym with s0 + count-weighted biases).
__global__ __launch_bounds__(256) void gemm1_kernel(
    const ushort* __restrict__ SA, const ushort* __restrict__ WcT,
    float* __restrict__ symOut)
{
    GEMM_PROLOGUE();
    int r = blockIdx.z;
    int row0 = blockIdx.y * 128, col0 = blockIdx.x * 128;
    gemm_core(SA + r * DD, 1536, WcT + r * DD, 1536, DD,
              row0, col0, tid, Als, Bls, acc);
    EPI_IDS();
#pragma unroll
    for (int nt = 0; nt < 4; nt++) {
        int col = col0 + wn * 64 + nt * 16 + l15;
#pragma unroll
        for (int mt = 0; mt < 4; mt++)
#pragma unroll
            for (int v = 0; v < 4; v++) {
                int row = row0 + wm * 64 + mt * 16 + quad * 4 + v;
                atomicAdd(&symOut[(size_t)row * DD + col], acc[mt][nt][v]);
            }
    }
}

// ----------------------------------------------------------------- gemm2 --
// symOut(fp32) @ Wbig^T. Col blocks 0..5: gelu + fused interp reduction
// (atomicAdd into outI pre-loaded with h2b). Col blocks 6..7: out0.
__global__ __launch_bounds__(256) void gemm2_kernel(
    const float* __restrict__ symOut, const ushort* __restrict__ WbT,
    const float* __restrict__ bbig, const float* __restrict__ h2W,
    float* __restrict__ out0, float* __restrict__ outI)
{
    GEMM_PROLOGUE();
    int row0 = blockIdx.y * 128, col0 = blockIdx.x * 128;
    gemm_core_f32A(symOut, 256, WbT, 256, 256, row0, col0, tid, Als, Bls, acc);
    EPI_IDS();
    if (col0 >= 768) {
#pragma unroll
        for (int nt = 0; nt < 4; nt++) {
            int c = col0 + wn * 64 + nt * 16 + l15;
            float bb = bbig[c];
#pragma unroll
            for (int mt = 0; mt < 4; mt++)
#pragma unroll
                for (int v = 0; v < 4; v++) {
                    int row = row0 + wm * 64 + mt * 16 + quad * 4 + v;
                    out0[(size_t)row * DD + (c - 768)] = acc[mt][nt][v] + bb;
                }
        }
    } else {
        int head = col0 >> 8;
        float part[4][4];
#pragma unroll
        for (int mt = 0; mt < 4; mt++)
#pragma unroll
            for (int v = 0; v < 4; v++) part[mt][v] = 0.f;
#pragma unroll
        for (int nt = 0; nt < 4; nt++) {
            int c = col0 + wn * 64 + nt * 16 + l15;
            float bb = bbig[c];
            float w2 = h2W[c];
#pragma unroll
            for (int mt = 0; mt < 4; mt++)
#pragma unroll
                for (int v = 0; v < 4; v++)
                    part[mt][v] += gelu_exact(acc[mt][nt][v] + bb) * w2;
        }
#pragma unroll
        for (int mt = 0; mt < 4; mt++)
#pragma unroll
            for (int v = 0; v < 4; v++) {
                float p = part[mt][v];
                p += __shfl_xor(p, 1); p += __shfl_xor(p, 2);
                p += __shfl_xor(p, 4); p += __shfl_xor(p, 8);
                if (l15 == 0) {
                    int row = row0 + wm * 64 + mt * 16 + quad * 4 + v;
                    atomicAdd(&outI[head * BNT + row], p);
                }
            }
    }
}

// ---------------------------------------------------------------- launch --
extern "C" void kernel_launch(void* const* d_in, const int* in_sizes, int n_in,
                              void* d_out, int out_size, void* d_ws, size_t ws_size,
                              hipStream_t stream)
{
    const int*   ids  = (const int*)d_in[0];
    const float* pos  = (const float*)d_in[1];
    const float* symt = (const float*)d_in[2];
    const float* layt = (const float*)d_in[3];
    const float* relW = (const float*)d_in[4];
    const float* relb = (const float*)d_in[5];
    const float* h1W  = (const float*)d_in[6];
    const float* h1b  = (const float*)d_in[7];
    const float* h2W  = (const float*)d_in[8];
    const float* h2b  = (const float*)d_in[9];
    const float* outW = (const float*)d_in[10];
    const float* outb = (const float*)d_in[11];
    float* out = (float*)d_out;
    float* ws  = (float*)d_ws;

    float* s0     = ws + OFF_S0;
    ushort* s0T   = (ushort*)(ws + OFF_S0T);
    ushort* SA    = (ushort*)(ws + OFF_SA);
    int*    cntp  = (int*)(ws + OFF_CNT);
    ushort* WcT   = (ushort*)(ws + OFF_WCT);
    ushort* WbT   = (ushort*)(ws + OFF_WBT);
    float*  bbig  = ws + OFF_BB;

    prep_kernel<<<1536, 256, 0, stream>>>(relW, h1W, outW, h1b, outb, WcT, WbT, bbig);
    gather_kernel<<<4096, 256, 0, stream>>>(ids, symt, layt, s0);
    transpose_kernel<<<dim3(8, 4, 8), 256, 0, stream>>>(s0, s0T);
    count_kernel<<<64, 256, 0, stream>>>(pos, cntp);
    init_interp_kernel<<<48, 256, 0, stream>>>(h2b, out + INTERP_OFF);
    init_sym_kernel<<<4096, 256, 0, stream>>>(s0, cntp, relb, out + SYM_OFF);
    agg_gemm<<<dim3(2, 4, 48), 256, 0, stream>>>(pos, s0T, SA);
    gemm1_kernel<<<dim3(2, 32, 6), 256, 0, stream>>>(SA, WcT, out + SYM_OFF);
    gemm2_kernel<<<dim3(8, 32), 256, 0, stream>>>(out + SYM_OFF, WbT,
                                                  bbig, h2W,
                                                  out + OUT0_OFF, out + INTERP_OFF);
}

// Round 7
// 203.558 us; speedup vs baseline: 1.1287x; 1.1287x over previous
//
#include <hip/hip_runtime.h>
#include <hip/hip_bf16.h>
#include <math.h>

#define BB 8
#define NN 512
#define DD 256
#define BNT 4096   // B*N

typedef __attribute__((ext_vector_type(8))) short short8;
typedef __attribute__((ext_vector_type(4))) float f32x4;

// Workspace layout (float offsets). ~16 MB.
#define OFF_S0    0u          // fp32 [4096][256]   s0
#define OFF_S0T   1048576u    // bf16 [8][256][512] s0 transposed per batch
#define OFF_SA    1572864u    // bf16 [4096][1536]  aggregated S (r-major cols)
#define OFF_WCT   4718592u    // bf16 [256][1536]   Wcat^T  (e rows, k=(r,d))
#define OFF_WBT   4915200u    // bf16 [1024][256]   Wbig^T  (c rows, k=d)
#define OFF_BB    5046272u    // fp32 [1024]        h1b|outb

// d_out layout (floats)
#define OUT0_OFF   0u        // output  [8][512][256]
#define INTERP_OFF 1048576u  // interp  [3][4096]
#define SYM_OFF    1060864u  // symbols [8][512][256]

__device__ __forceinline__ float gelu_exact(float x) {
    return 0.5f * x * (1.0f + erff(x * 0.70710678118654752f));
}

__device__ __forceinline__ ushort f2bf(float x) {
    __hip_bfloat16 h = __float2bfloat16(x);
    union { __hip_bfloat16 b; ushort u; } cv;
    cv.b = h;
    return cv.u;
}

__device__ __forceinline__ int rel_of(float dx, float dy) {
    if (dy >  0.5f) return 0;
    if (dy < -0.5f) return 1;
    if (dx < -0.5f) return 2;
    if (dx >  0.5f) return 3;
    if (fabsf(dx) < 0.3f && fabsf(dy) < 0.3f) return 4;
    return 5;
}

// ====== 64x64-tile MFMA core pieces (4 waves, each 2x2 of 16x16x32) =======
// Staging: thread t loads 16B chunk: row sm=t>>2 (0..63), k-chunk sq=t&3.
// LDS [chunk(k/8)][row] ushort8. Fragments (m89/m91 verified):
// A: m=lane&15, k=quad*8+j ; B: n=lane&15 ; C/D: col=lane&15, row=quad*4+reg.

#define TILE_IDS()                                             \
    const int lane = tid & 63, w = tid >> 6;                   \
    const int wm = w >> 1, wn = w & 1;                         \
    const int quad = lane >> 4, l15 = lane & 15;               \
    const int sm = tid >> 2, sq = tid & 3;

#define MFMA_STEP()                                                          \
    {                                                                        \
        short8 af[2], bfr[2];                                                \
        _Pragma("unroll")                                                    \
        for (int mt = 0; mt < 2; mt++)                                       \
            af[mt] = *(const short8*)&Als[(quad * 64 + wm * 32 + mt * 16 + l15) * 8]; \
        _Pragma("unroll")                                                    \
        for (int nt = 0; nt < 2; nt++)                                       \
            bfr[nt] = *(const short8*)&Bls[(quad * 64 + wn * 32 + nt * 16 + l15) * 8]; \
        _Pragma("unroll")                                                    \
        for (int mt = 0; mt < 2; mt++)                                       \
            _Pragma("unroll")                                                \
            for (int nt = 0; nt < 2; nt++)                                   \
                acc[mt][nt] = __builtin_amdgcn_mfma_f32_16x16x32_bf16(       \
                    af[mt], bfr[nt], acc[mt][nt], 0, 0, 0);                  \
    }

// ---------------------------------------------------------------- prep ----
__global__ __launch_bounds__(256) void prep_kernel(
    const float* __restrict__ relW, const float* __restrict__ h1W,
    const float* __restrict__ outW, const float* __restrict__ h1b,
    const float* __restrict__ outb, const float* __restrict__ h2b,
    ushort* __restrict__ WcT, ushort* __restrict__ WbT,
    float* __restrict__ bbig, float* __restrict__ outI)
{
    int idx = blockIdx.x * 256 + threadIdx.x;    // grid 1536 -> 393216
    {
        int e = idx / 1536, k = idx - e * 1536;
        int r = k >> 8, d = k & 255;
        WcT[idx] = f2bf(relW[(r * DD + d) * DD + e]);
    }
    if (idx < 262144) {
        int c = idx >> 8, d = idx & 255;
        float v;
        if (c < 768) { int r = c >> 8, e = c & 255; v = h1W[(r * DD + d) * DD + e]; }
        else         { v = outW[d * DD + (c - 768)]; }
        WbT[idx] = f2bf(v);
    }
    if (idx < 3 * BNT) outI[idx] = h2b[idx >> 12];
    if (idx < 1024) bbig[idx] = (idx < 768) ? h1b[idx] : outb[idx - 768];
}

// ----------------------------------------------------- gather+transpose ---
// Block = (itile, dtile, b): writes s0 fp32 [b][i][d] and s0T bf16 [b][d][i].
__global__ __launch_bounds__(256) void gather_transpose_kernel(
    const int* __restrict__ ids, const float* __restrict__ symt,
    const float* __restrict__ layt, float* __restrict__ s0,
    ushort* __restrict__ s0T)
{
    __shared__ float tile[64][65];
    __shared__ int idsL[64];
    int b = blockIdx.z, i0 = blockIdx.x * 64, d0 = blockIdx.y * 64;
    int x = threadIdx.x & 63, g = threadIdx.x >> 6;
    if (threadIdx.x < 64) idsL[threadIdx.x] = ids[b * NN + i0 + threadIdx.x];
    __syncthreads();
#pragma unroll
    for (int k = 0; k < 16; k++) {
        int il = g * 16 + k;
        int id = idsL[il];
        float v = symt[id * DD + d0 + x] + layt[id * DD + d0 + x];
        tile[il][x] = v;
        s0[((size_t)(b * NN) + i0 + il) * DD + d0 + x] = v;
    }
    __syncthreads();
#pragma unroll
    for (int k = 0; k < 16; k++) {
        int dl = g * 16 + k;
        s0T[((size_t)(b * DD) + d0 + dl) * NN + i0 + x] = f2bf(tile[x][dl]);
    }
}

// ------------------------------------------------------ count + init sym --
// Block = (b, 64-j tile). Phase 1: relation counts -> LDS. Phase 2:
// symOut[row] = s0[row] + sum_r cnt_r * relb_r (base for gemm1 atomics).
__global__ __launch_bounds__(256) void count_init_sym_kernel(
    const float* __restrict__ positions, const float* __restrict__ s0,
    const float* __restrict__ relb, float* __restrict__ symOut)
{
    int b = blockIdx.x >> 3;
    int jt = blockIdx.x & 7;
    int tid = threadIdx.x, lane = tid & 63, w = tid >> 6;
    __shared__ float px[NN], py[NN];
    __shared__ float cl[64][6];
    for (int i = tid; i < NN; i += 256) {
        float2 p = ((const float2*)positions)[b * NN + i];
        px[i] = p.x; py[i] = p.y;
    }
    __syncthreads();
    for (int jj = 0; jj < 16; jj++) {
        int jl = w * 16 + jj;
        int j = jt * 64 + jl;
        float xj = px[j], yj = py[j];
        int c[6] = {0, 0, 0, 0, 0, 0};
        for (int it = 0; it < 8; it++) {
            int i = it * 64 + lane;
            int r = rel_of(xj - px[i], yj - py[i]);
            if (i == j) r = 6;
#pragma unroll
            for (int rr = 0; rr < 6; rr++) c[rr] += (r == rr) ? 1 : 0;
        }
#pragma unroll
        for (int rr = 0; rr < 6; rr++) {
            int v = c[rr];
            v += __shfl_xor(v, 32); v += __shfl_xor(v, 16);
            v += __shfl_xor(v, 8);  v += __shfl_xor(v, 4);
            v += __shfl_xor(v, 2);  v += __shfl_xor(v, 1);
            if (lane == 0) cl[jl][rr] = (float)v;
        }
    }
    __syncthreads();
    float rb[6];
#pragma unroll
    for (int rr = 0; rr < 6; rr++) rb[rr] = relb[rr * DD + tid];
    size_t base = (size_t)(b * NN + jt * 64) * DD + tid;
    for (int jl = 0; jl < 64; jl++) {
        float v = s0[base + (size_t)jl * DD];
#pragma unroll
        for (int rr = 0; rr < 6; rr++) v += cl[jl][rr] * rb[rr];
        symOut[base + (size_t)jl * DD] = v;
    }
}

// ------------------------------------------------------------- agg gemm ---
// SA[b*512+j][r*256+d] = sum_i 1[rel(i,j)=r, i!=j] * s0[b][i][d].
// 64x64 tile; one-hot A generated from LDS positions at staging.
// Grid (4 dtile, 8 jtile, 48 b*r) = 1536 blocks (~6/CU).
__global__ __launch_bounds__(256) void agg_gemm(
    const float* __restrict__ positions, const ushort* __restrict__ s0T,
    ushort* __restrict__ SA)
{
    __shared__ ushort Als[2048], Bls[2048];
    __shared__ float px[NN], py[NN];
    int tid = threadIdx.x;
    int z = blockIdx.z, b = z / 6, r = z - b * 6;
    int row0 = blockIdx.y * 64, col0 = blockIdx.x * 64;
    for (int i = tid; i < NN; i += 256) {
        float2 p = ((const float2*)positions)[b * NN + i];
        px[i] = p.x; py[i] = p.y;
    }
    TILE_IDS();
    f32x4 acc[2][2];
#pragma unroll
    for (int mt = 0; mt < 2; mt++)
#pragma unroll
        for (int nt = 0; nt < 2; nt++) acc[mt][nt] = (f32x4){0.f, 0.f, 0.f, 0.f};
    const int j = row0 + sm;
    const ushort* gB = s0T + (size_t)b * DD * NN + (size_t)(col0 + sm) * NN + sq * 8;
    __syncthreads();
    const float xj = px[j], yj = py[j];

    for (int k0 = 0; k0 < NN; k0 += 32) {
        uint4 bv = *(const uint4*)(gB + k0);
        union alignas(16) { ushort u[8]; uint4 v; } am;
#pragma unroll
        for (int t = 0; t < 8; t++) {
            int i = k0 + sq * 8 + t;
            int rr = rel_of(xj - px[i], yj - py[i]);
            am.u[t] = (rr == r && i != j) ? 0x3F80 : 0;
        }
        __syncthreads();
        *(uint4*)&Als[(sq * 64 + sm) * 8] = am.v;
        *(uint4*)&Bls[(sq * 64 + sm) * 8] = bv;
        __syncthreads();
        MFMA_STEP();
    }
#pragma unroll
    for (int mt = 0; mt < 2; mt++)
#pragma unroll
        for (int nt = 0; nt < 2; nt++)
#pragma unroll
            for (int v = 0; v < 4; v++) {
                int row = row0 + wm * 32 + mt * 16 + quad * 4 + v;
                int col = col0 + wn * 32 + nt * 16 + l15;
                SA[(size_t)(b * NN + row) * 1536 + r * DD + col] =
                    f2bf(acc[mt][nt][v]);
            }
}

// ----------------------------------------------------------------- gemm1 --
// Split-K over r-pairs: grid (4, 64, 3) = 768 blocks (~3/CU), K=512 each.
// atomicAdd into symOut (pre-initialized by count_init_sym).
__global__ __launch_bounds__(256) void gemm1_kernel(
    const ushort* __restrict__ SA, const ushort* __restrict__ WcT,
    float* __restrict__ symOut)
{
    __shared__ ushort Als[2048], Bls[2048];
    int tid = threadIdx.x;
    int rg = blockIdx.z;                 // k-slice [rg*512, rg*512+512)
    int row0 = blockIdx.y * 64, col0 = blockIdx.x * 64;
    TILE_IDS();
    f32x4 acc[2][2];
#pragma unroll
    for (int mt = 0; mt < 2; mt++)
#pragma unroll
        for (int nt = 0; nt < 2; nt++) acc[mt][nt] = (f32x4){0.f, 0.f, 0.f, 0.f};
    const ushort* gA = SA  + (size_t)(row0 + sm) * 1536 + rg * 512 + sq * 8;
    const ushort* gB = WcT + (size_t)(col0 + sm) * 1536 + rg * 512 + sq * 8;

    for (int k0 = 0; k0 < 512; k0 += 32) {
        uint4 av = *(const uint4*)(gA + k0);
        uint4 bv = *(const uint4*)(gB + k0);
        __syncthreads();
        *(uint4*)&Als[(sq * 64 + sm) * 8] = av;
        *(uint4*)&Bls[(sq * 64 + sm) * 8] = bv;
        __syncthreads();
        MFMA_STEP();
    }
#pragma unroll
    for (int mt = 0; mt < 2; mt++)
#pragma unroll
        for (int nt = 0; nt < 2; nt++)
#pragma unroll
            for (int v = 0; v < 4; v++) {
                int row = row0 + wm * 32 + mt * 16 + quad * 4 + v;
                int col = col0 + wn * 32 + nt * 16 + l15;
                atomicAdd(&symOut[(size_t)row * DD + col], acc[mt][nt][v]);
            }
}

// ----------------------------------------------------------------- gemm2 --
// symOut(fp32, converted at staging) @ Wbig^T. Grid (16, 64) = 1024 blocks.
// Col tiles 0..11: gelu + fused interp reduce (atomicAdd into outI, which
// prep pre-loads with h2b). Col tiles 12..15: output projection.
__global__ __launch_bounds__(256) void gemm2_kernel(
    const float* __restrict__ symOut, const ushort* __restrict__ WbT,
    const float* __restrict__ bbig, const float* __restrict__ h2W,
    float* __restrict__ out0, float* __restrict__ outI)
{
    __shared__ ushort Als[2048], Bls[2048];
    int tid = threadIdx.x;
    int row0 = blockIdx.y * 64, col0 = blockIdx.x * 64;
    TILE_IDS();
    f32x4 acc[2][2];
#pragma unroll
    for (int mt = 0; mt < 2; mt++)
#pragma unroll
        for (int nt = 0; nt < 2; nt++) acc[mt][nt] = (f32x4){0.f, 0.f, 0.f, 0.f};
    const float*  gA = symOut + (size_t)(row0 + sm) * DD + sq * 8;
    const ushort* gB = WbT    + (size_t)(col0 + sm) * DD + sq * 8;

    for (int k0 = 0; k0 < DD; k0 += 32) {
        union alignas(16) { float f[8]; float4 v4[2]; } af32;
        af32.v4[0] = *(const float4*)(gA + k0);
        af32.v4[1] = *(const float4*)(gA + k0 + 4);
        uint4 bv = *(const uint4*)(gB + k0);
        union alignas(16) { ushort u[8]; uint4 v; } am;
#pragma unroll
        for (int t = 0; t < 8; t++) am.u[t] = f2bf(af32.f[t]);
        __syncthreads();
        *(uint4*)&Als[(sq * 64 + sm) * 8] = am.v;
        *(uint4*)&Bls[(sq * 64 + sm) * 8] = bv;
        __syncthreads();
        MFMA_STEP();
    }
    if (col0 >= 768) {
#pragma unroll
        for (int nt = 0; nt < 2; nt++) {
            int c = col0 + wn * 32 + nt * 16 + l15;
            float bb = bbig[c];
#pragma unroll
            for (int mt = 0; mt < 2; mt++)
#pragma unroll
                for (int v = 0; v < 4; v++) {
                    int row = row0 + wm * 32 + mt * 16 + quad * 4 + v;
                    out0[(size_t)row * DD + (c - 768)] = acc[mt][nt][v] + bb;
                }
        }
    } else {
        int head = col0 >> 8;
        float part[2][4];
#pragma unroll
        for (int mt = 0; mt < 2; mt++)
#pragma unroll
            for (int v = 0; v < 4; v++) part[mt][v] = 0.f;
#pragma unroll
        for (int nt = 0; nt < 2; nt++) {
            int c = col0 + wn * 32 + nt * 16 + l15;
            float bb = bbig[c];
            float w2 = h2W[c];
#pragma unroll
            for (int mt = 0; mt < 2; mt++)
#pragma unroll
                for (int v = 0; v < 4; v++)
                    part[mt][v] += gelu_exact(acc[mt][nt][v] + bb) * w2;
        }
#pragma unroll
        for (int mt = 0; mt < 2; mt++)
#pragma unroll
            for (int v = 0; v < 4; v++) {
                float p = part[mt][v];
                p += __shfl_xor(p, 1); p += __shfl_xor(p, 2);
                p += __shfl_xor(p, 4); p += __shfl_xor(p, 8);
                if (l15 == 0) {
                    int row = row0 + wm * 32 + mt * 16 + quad * 4 + v;
                    atomicAdd(&outI[head * BNT + row], p);
                }
            }
    }
}

// ---------------------------------------------------------------- launch --
extern "C" void kernel_launch(void* const* d_in, const int* in_sizes, int n_in,
                              void* d_out, int out_size, void* d_ws, size_t ws_size,
                              hipStream_t stream)
{
    const int*   ids  = (const int*)d_in[0];
    const float* pos  = (const float*)d_in[1];
    const float* symt = (const float*)d_in[2];
    const float* layt = (const float*)d_in[3];
    const float* relW = (const float*)d_in[4];
    const float* relb = (const float*)d_in[5];
    const float* h1W  = (const float*)d_in[6];
    const float* h1b  = (const float*)d_in[7];
    const float* h2W  = (const float*)d_in[8];
    const float* h2b  = (const float*)d_in[9];
    const float* outW = (const float*)d_in[10];
    const float* outb = (const float*)d_in[11];
    float* out = (float*)d_out;
    float* ws  = (float*)d_ws;

    float*  s0   = ws + OFF_S0;
    ushort* s0T  = (ushort*)(ws + OFF_S0T);
    ushort* SA   = (ushort*)(ws + OFF_SA);
    ushort* WcT  = (ushort*)(ws + OFF_WCT);
    ushort* WbT  = (ushort*)(ws + OFF_WBT);
    float*  bbig = ws + OFF_BB;

    prep_kernel<<<1536, 256, 0, stream>>>(relW, h1W, outW, h1b, outb, h2b,
                                          WcT, WbT, bbig, out + INTERP_OFF);
    gather_transpose_kernel<<<dim3(8, 4, 8), 256, 0, stream>>>(ids, symt, layt,
                                                               s0, s0T);
    count_init_sym_kernel<<<64, 256, 0, stream>>>(pos, s0, relb, out + SYM_OFF);
    agg_gemm<<<dim3(4, 8, 48), 256, 0, stream>>>(pos, s0T, SA);
    gemm1_kernel<<<dim3(4, 64, 3), 256, 0, stream>>>(SA, WcT, out + SYM_OFF);
    gemm2_kernel<<<dim3(16, 64), 256, 0, stream>>>(out + SYM_OFF, WbT,
                                                   bbig, h2W,
                                                   out + OUT0_OFF, out + INTERP_OFF);
}

// Round 8
// 144.847 us; speedup vs baseline: 1.5862x; 1.4053x over previous
//
#include <hip/hip_runtime.h>
#include <hip/hip_bf16.h>
#include <math.h>

#define BB 8
#define NN 512
#define DD 256
#define BNT 4096   // B*N

typedef __attribute__((ext_vector_type(8))) short short8;
typedef __attribute__((ext_vector_type(4))) float f32x4;

// Workspace layout (float offsets). ~22.3 MB.
#define OFF_S0    0u          // fp32 [4096][256]   s0
#define OFF_S0T   1048576u    // bf16 [8][256][512] s0 transposed per batch
#define OFF_SA    1572864u    // bf16 [4096][1536]  aggregated S (r-major cols)
#define OFF_WCT   4718592u    // bf16 [256][1536]   Wcat^T  (e rows, k=(r,d))
#define OFF_WBT   4915200u    // bf16 [1024][256]   Wbig^T  (c rows, k=d)
#define OFF_BB    5046272u    // fp32 [1024]        h1b|outb
#define OFF_REL   5047296u    // u8   [8][512][512] relation codes (self=6)

// d_out layout (floats)
#define OUT0_OFF   0u        // output  [8][512][256]
#define INTERP_OFF 1048576u  // interp  [3][4096]
#define SYM_OFF    1060864u  // symbols [8][512][256]

__device__ __forceinline__ float gelu_exact(float x) {
    return 0.5f * x * (1.0f + erff(x * 0.70710678118654752f));
}

__device__ __forceinline__ ushort f2bf(float x) {
    __hip_bfloat16 h = __float2bfloat16(x);
    union { __hip_bfloat16 b; ushort u; } cv;
    cv.b = h;
    return cv.u;
}

// Branch-free: ternary chain -> v_cndmask (no exec-mask divergence).
// Priority (reference if/elif order) preserved by applying in reverse.
__device__ __forceinline__ int rel_of(float dx, float dy) {
    int r = (fabsf(dx) < 0.3f && fabsf(dy) < 0.3f) ? 4 : 5;
    r = (dx >  0.5f) ? 3 : r;
    r = (dx < -0.5f) ? 2 : r;
    r = (dy < -0.5f) ? 1 : r;
    r = (dy >  0.5f) ? 0 : r;
    return r;
}

// ====== 64x64-tile MFMA core pieces (4 waves, each 2x2 of 16x16x32) =======
// Staging: thread t loads 16B chunk: row sm=t>>2 (0..63), k-chunk sq=t&3.
// LDS [chunk(k/8)][row] ushort8. Fragments (m89/m91 verified):
// A: m=lane&15, k=quad*8+j ; B: n=lane&15 ; C/D: col=lane&15, row=quad*4+reg.

#define TILE_IDS()                                             \
    const int lane = tid & 63, w = tid >> 6;                   \
    const int wm = w >> 1, wn = w & 1;                         \
    const int quad = lane >> 4, l15 = lane & 15;               \
    const int sm = tid >> 2, sq = tid & 3;

#define MFMA_STEP()                                                          \
    {                                                                        \
        short8 af[2], bfr[2];                                                \
        _Pragma("unroll")                                                    \
        for (int mt = 0; mt < 2; mt++)                                       \
            af[mt] = *(const short8*)&Als[(quad * 64 + wm * 32 + mt * 16 + l15) * 8]; \
        _Pragma("unroll")                                                    \
        for (int nt = 0; nt < 2; nt++)                                       \
            bfr[nt] = *(const short8*)&Bls[(quad * 64 + wn * 32 + nt * 16 + l15) * 8]; \
        _Pragma("unroll")                                                    \
        for (int mt = 0; mt < 2; mt++)                                       \
            _Pragma("unroll")                                                \
            for (int nt = 0; nt < 2; nt++)                                   \
                acc[mt][nt] = __builtin_amdgcn_mfma_f32_16x16x32_bf16(       \
                    af[mt], bfr[nt], acc[mt][nt], 0, 0, 0);                  \
    }

// ---------------------------------------------------------------- prep ----
__global__ __launch_bounds__(256) void prep_kernel(
    const float* __restrict__ relW, const float* __restrict__ h1W,
    const float* __restrict__ outW, const float* __restrict__ h1b,
    const float* __restrict__ outb, const float* __restrict__ h2b,
    ushort* __restrict__ WcT, ushort* __restrict__ WbT,
    float* __restrict__ bbig, float* __restrict__ outI)
{
    int idx = blockIdx.x * 256 + threadIdx.x;    // grid 1536 -> 393216
    {
        int e = idx / 1536, k = idx - e * 1536;
        int r = k >> 8, d = k & 255;
        WcT[idx] = f2bf(relW[(r * DD + d) * DD + e]);
    }
    if (idx < 262144) {
        int c = idx >> 8, d = idx & 255;
        float v;
        if (c < 768) { int r = c >> 8, e = c & 255; v = h1W[(r * DD + d) * DD + e]; }
        else         { v = outW[d * DD + (c - 768)]; }
        WbT[idx] = f2bf(v);
    }
    if (idx < 3 * BNT) outI[idx] = h2b[idx >> 12];
    if (idx < 1024) bbig[idx] = (idx < 768) ? h1b[idx] : outb[idx - 768];
}

// ----------------------------------------------------- gather+transpose ---
__global__ __launch_bounds__(256) void gather_transpose_kernel(
    const int* __restrict__ ids, const float* __restrict__ symt,
    const float* __restrict__ layt, float* __restrict__ s0,
    ushort* __restrict__ s0T)
{
    __shared__ float tile[64][65];
    __shared__ int idsL[64];
    int b = blockIdx.z, i0 = blockIdx.x * 64, d0 = blockIdx.y * 64;
    int x = threadIdx.x & 63, g = threadIdx.x >> 6;
    if (threadIdx.x < 64) idsL[threadIdx.x] = ids[b * NN + i0 + threadIdx.x];
    __syncthreads();
#pragma unroll
    for (int k = 0; k < 16; k++) {
        int il = g * 16 + k;
        int id = idsL[il];
        float v = symt[id * DD + d0 + x] + layt[id * DD + d0 + x];
        tile[il][x] = v;
        s0[((size_t)(b * NN) + i0 + il) * DD + d0 + x] = v;
    }
    __syncthreads();
#pragma unroll
    for (int k = 0; k < 16; k++) {
        int dl = g * 16 + k;
        s0T[((size_t)(b * DD) + d0 + dl) * NN + i0 + x] = f2bf(tile[x][dl]);
    }
}

// ---------------------------------------------------- classify+init sym ---
// Grid 512: b = blk>>6, j0 = (blk&63)*8. Classifies each (i,j) pair ONCE,
// writes u8 codes rel[b][j][i] (self=6), per-(j,r) counts via shuffle,
// then symOut[row] = s0[row] + sum_r cnt_r*relb_r for its 8 rows.
__global__ __launch_bounds__(256) void classify_init_sym_kernel(
    const float* __restrict__ positions, const float* __restrict__ s0,
    const float* __restrict__ relb, unsigned char* __restrict__ rel,
    float* __restrict__ symOut)
{
    int b = blockIdx.x >> 6;
    int j0 = (blockIdx.x & 63) << 3;
    int tid = threadIdx.x;
    int jl = tid >> 5, sub = tid & 31;     // 8 j's x 32 workers
    __shared__ float px[NN], py[NN];
    __shared__ float cl[8][6];
    for (int i = tid; i < NN; i += 256) {
        float2 p = ((const float2*)positions)[b * NN + i];
        px[i] = p.x; py[i] = p.y;
    }
    __syncthreads();
    int j = j0 + jl;
    float xj = px[j], yj = py[j];
    int c[6] = {0, 0, 0, 0, 0, 0};
    union { unsigned char u8[16]; uint4 v; } codes;
#pragma unroll
    for (int t = 0; t < 16; t++) {
        int i = sub * 16 + t;
        int r = rel_of(xj - px[i], yj - py[i]);
        r = (i == j) ? 6 : r;
        codes.u8[t] = (unsigned char)r;
#pragma unroll
        for (int rr = 0; rr < 6; rr++) c[rr] += (r == rr) ? 1 : 0;
    }
    *(uint4*)&rel[((size_t)(b * NN + j)) * NN + sub * 16] = codes.v;
#pragma unroll
    for (int rr = 0; rr < 6; rr++) {
        int v = c[rr];
        v += __shfl_xor(v, 16); v += __shfl_xor(v, 8);
        v += __shfl_xor(v, 4);  v += __shfl_xor(v, 2);
        v += __shfl_xor(v, 1);
        if (sub == 0) cl[jl][rr] = (float)v;
    }
    __syncthreads();
    float rb[6];
#pragma unroll
    for (int rr = 0; rr < 6; rr++) rb[rr] = relb[rr * DD + tid];
#pragma unroll
    for (int q = 0; q < 8; q++) {
        size_t row = (size_t)(b * NN + j0 + q);
        float v = s0[row * DD + tid];
#pragma unroll
        for (int rr = 0; rr < 6; rr++) v += cl[q][rr] * rb[rr];
        symOut[row * DD + tid] = v;
    }
}

// ------------------------------------------------------------- agg gemm ---
// SA[b*512+j][r*256+d] = sum_i 1[rel(i,j)=r] * s0[b][i][d].
// A-tile one-hot generated from precomputed u8 codes (8B load + 8 cmpsel).
// Grid (4 dtile, 8 jtile, 48 b*r) = 1536 blocks (~6/CU).
__global__ __launch_bounds__(256) void agg_gemm(
    const unsigned char* __restrict__ rel, const ushort* __restrict__ s0T,
    ushort* __restrict__ SA)
{
    __shared__ ushort Als[2048], Bls[2048];
    int tid = threadIdx.x;
    int z = blockIdx.z, b = z / 6, r = z - b * 6;
    int row0 = blockIdx.y * 64, col0 = blockIdx.x * 64;
    TILE_IDS();
    f32x4 acc[2][2];
#pragma unroll
    for (int mt = 0; mt < 2; mt++)
#pragma unroll
        for (int nt = 0; nt < 2; nt++) acc[mt][nt] = (f32x4){0.f, 0.f, 0.f, 0.f};
    const unsigned char* gC = rel + ((size_t)(b * NN + row0 + sm)) * NN + sq * 8;
    const ushort* gB = s0T + (size_t)b * DD * NN + (size_t)(col0 + sm) * NN + sq * 8;

    for (int k0 = 0; k0 < NN; k0 += 32) {
        uint2 cw = *(const uint2*)(gC + k0);
        uint4 bv = *(const uint4*)(gB + k0);
        union alignas(16) { ushort u[8]; uint4 v; } am;
#pragma unroll
        for (int t = 0; t < 8; t++) {
            unsigned int word = (t < 4) ? cw.x : cw.y;
            unsigned int code = (word >> (8 * (t & 3))) & 255u;
            am.u[t] = (code == (unsigned)r) ? 0x3F80 : 0;
        }
        __syncthreads();
        *(uint4*)&Als[(sq * 64 + sm) * 8] = am.v;
        *(uint4*)&Bls[(sq * 64 + sm) * 8] = bv;
        __syncthreads();
        MFMA_STEP();
    }
#pragma unroll
    for (int mt = 0; mt < 2; mt++)
#pragma unroll
        for (int nt = 0; nt < 2; nt++)
#pragma unroll
            for (int v = 0; v < 4; v++) {
                int row = row0 + wm * 32 + mt * 16 + quad * 4 + v;
                int col = col0 + wn * 32 + nt * 16 + l15;
                SA[(size_t)(b * NN + row) * 1536 + r * DD + col] =
                    f2bf(acc[mt][nt][v]);
            }
}

// ----------------------------------------------------------------- gemm1 --
// Split-K over r-pairs: grid (4, 64, 3) = 768 blocks, K=512 each.
// atomicAdd into symOut (pre-initialized by classify_init_sym).
__global__ __launch_bounds__(256) void gemm1_kernel(
    const ushort* __restrict__ SA, const ushort* __restrict__ WcT,
    float* __restrict__ symOut)
{
    __shared__ ushort Als[2048], Bls[2048];
    int tid = threadIdx.x;
    int rg = blockIdx.z;                 // k-slice [rg*512, rg*512+512)
    int row0 = blockIdx.y * 64, col0 = blockIdx.x * 64;
    TILE_IDS();
    f32x4 acc[2][2];
#pragma unroll
    for (int mt = 0; mt < 2; mt++)
#pragma unroll
        for (int nt = 0; nt < 2; nt++) acc[mt][nt] = (f32x4){0.f, 0.f, 0.f, 0.f};
    const ushort* gA = SA  + (size_t)(row0 + sm) * 1536 + rg * 512 + sq * 8;
    const ushort* gB = WcT + (size_t)(col0 + sm) * 1536 + rg * 512 + sq * 8;

    for (int k0 = 0; k0 < 512; k0 += 32) {
        uint4 av = *(const uint4*)(gA + k0);
        uint4 bv = *(const uint4*)(gB + k0);
        __syncthreads();
        *(uint4*)&Als[(sq * 64 + sm) * 8] = av;
        *(uint4*)&Bls[(sq * 64 + sm) * 8] = bv;
        __syncthreads();
        MFMA_STEP();
    }
#pragma unroll
    for (int mt = 0; mt < 2; mt++)
#pragma unroll
        for (int nt = 0; nt < 2; nt++)
#pragma unroll
            for (int v = 0; v < 4; v++) {
                int row = row0 + wm * 32 + mt * 16 + quad * 4 + v;
                int col = col0 + wn * 32 + nt * 16 + l15;
                atomicAdd(&symOut[(size_t)row * DD + col], acc[mt][nt][v]);
            }
}

// ----------------------------------------------------------------- gemm2 --
__global__ __launch_bounds__(256) void gemm2_kernel(
    const float* __restrict__ symOut, const ushort* __restrict__ WbT,
    const float* __restrict__ bbig, const float* __restrict__ h2W,
    float* __restrict__ out0, float* __restrict__ outI)
{
    __shared__ ushort Als[2048], Bls[2048];
    int tid = threadIdx.x;
    int row0 = blockIdx.y * 64, col0 = blockIdx.x * 64;
    TILE_IDS();
    f32x4 acc[2][2];
#pragma unroll
    for (int mt = 0; mt < 2; mt++)
#pragma unroll
        for (int nt = 0; nt < 2; nt++) acc[mt][nt] = (f32x4){0.f, 0.f, 0.f, 0.f};
    const float*  gA = symOut + (size_t)(row0 + sm) * DD + sq * 8;
    const ushort* gB = WbT    + (size_t)(col0 + sm) * DD + sq * 8;

    for (int k0 = 0; k0 < DD; k0 += 32) {
        union alignas(16) { float f[8]; float4 v4[2]; } af32;
        af32.v4[0] = *(const float4*)(gA + k0);
        af32.v4[1] = *(const float4*)(gA + k0 + 4);
        uint4 bv = *(const uint4*)(gB + k0);
        union alignas(16) { ushort u[8]; uint4 v; } am;
#pragma unroll
        for (int t = 0; t < 8; t++) am.u[t] = f2bf(af32.f[t]);
        __syncthreads();
        *(uint4*)&Als[(sq * 64 + sm) * 8] = am.v;
        *(uint4*)&Bls[(sq * 64 + sm) * 8] = bv;
        __syncthreads();
        MFMA_STEP();
    }
    if (col0 >= 768) {
#pragma unroll
        for (int nt = 0; nt < 2; nt++) {
            int c = col0 + wn * 32 + nt * 16 + l15;
            float bb = bbig[c];
#pragma unroll
            for (int mt = 0; mt < 2; mt++)
#pragma unroll
                for (int v = 0; v < 4; v++) {
                    int row = row0 + wm * 32 + mt * 16 + quad * 4 + v;
                    out0[(size_t)row * DD + (c - 768)] = acc[mt][nt][v] + bb;
                }
        }
    } else {
        int head = col0 >> 8;
        float part[2][4];
#pragma unroll
        for (int mt = 0; mt < 2; mt++)
#pragma unroll
            for (int v = 0; v < 4; v++) part[mt][v] = 0.f;
#pragma unroll
        for (int nt = 0; nt < 2; nt++) {
            int c = col0 + wn * 32 + nt * 16 + l15;
            float bb = bbig[c];
            float w2 = h2W[c];
#pragma unroll
            for (int mt = 0; mt < 2; mt++)
#pragma unroll
                for (int v = 0; v < 4; v++)
                    part[mt][v] += gelu_exact(acc[mt][nt][v] + bb) * w2;
        }
#pragma unroll
        for (int mt = 0; mt < 2; mt++)
#pragma unroll
            for (int v = 0; v < 4; v++) {
                float p = part[mt][v];
                p += __shfl_xor(p, 1); p += __shfl_xor(p, 2);
                p += __shfl_xor(p, 4); p += __shfl_xor(p, 8);
                if (l15 == 0) {
                    int row = row0 + wm * 32 + mt * 16 + quad * 4 + v;
                    atomicAdd(&outI[head * BNT + row], p);
                }
            }
    }
}

// ---------------------------------------------------------------- launch --
extern "C" void kernel_launch(void* const* d_in, const int* in_sizes, int n_in,
                              void* d_out, int out_size, void* d_ws, size_t ws_size,
                              hipStream_t stream)
{
    const int*   ids  = (const int*)d_in[0];
    const float* pos  = (const float*)d_in[1];
    const float* symt = (const float*)d_in[2];
    const float* layt = (const float*)d_in[3];
    const float* relW = (const float*)d_in[4];
    const float* relb = (const float*)d_in[5];
    const float* h1W  = (const float*)d_in[6];
    const float* h1b  = (const float*)d_in[7];
    const float* h2W  = (const float*)d_in[8];
    const float* h2b  = (const float*)d_in[9];
    const float* outW = (const float*)d_in[10];
    const float* outb = (const float*)d_in[11];
    float* out = (float*)d_out;
    float* ws  = (float*)d_ws;

    float*  s0   = ws + OFF_S0;
    ushort* s0T  = (ushort*)(ws + OFF_S0T);
    ushort* SA   = (ushort*)(ws + OFF_SA);
    ushort* WcT  = (ushort*)(ws + OFF_WCT);
    ushort* WbT  = (ushort*)(ws + OFF_WBT);
    float*  bbig = ws + OFF_BB;
    unsigned char* rel = (unsigned char*)(ws + OFF_REL);

    prep_kernel<<<1536, 256, 0, stream>>>(relW, h1W, outW, h1b, outb, h2b,
                                          WcT, WbT, bbig, out + INTERP_OFF);
    gather_transpose_kernel<<<dim3(8, 4, 8), 256, 0, stream>>>(ids, symt, layt,
                                                               s0, s0T);
    classify_init_sym_kernel<<<512, 256, 0, stream>>>(pos, s0, relb, rel,
                                                      out + SYM_OFF);
    agg_gemm<<<dim3(4, 8, 48), 256, 0, stream>>>(rel, s0T, SA);
    gemm1_kernel<<<dim3(4, 64, 3), 256, 0, stream>>>(SA, WcT, out + SYM_OFF);
    gemm2_kernel<<<dim3(16, 64), 256, 0, stream>>>(out + SYM_OFF, WbT,
                                                   bbig, h2W,
                                                   out + OUT0_OFF, out + INTERP_OFF);
}

// Round 9
// 143.693 us; speedup vs baseline: 1.5989x; 1.0080x over previous
//
#include <hip/hip_runtime.h>
#include <hip/hip_bf16.h>
#include <math.h>

#define BB 8
#define NN 512
#define DD 256
#define BNT 4096   // B*N

typedef __attribute__((ext_vector_type(8))) short short8;
typedef __attribute__((ext_vector_type(4))) float f32x4;

// Workspace layout (float offsets). ~18 MB.
#define OFF_S0B   0u          // bf16 [4096][256]      s0 row-major (gemmT B)
#define OFF_TT    524288u     // bf16 [8][256][3072]   TT[b][e][r*512+i] = T_r[i][e]+relb_r[e]
#define OFF_WCT   6815744u    // bf16 [256][1536]      WcT[e][r*256+d] = relW[r][d][e]
#define OFF_WBT   7012352u    // bf16 [1024][256]      Wbig^T (c rows, k=d)
#define OFF_BB    7143424u    // fp32 [1024]           h1b|outb
#define OFF_REL   7144448u    // u8   [8][512][512]    relation codes (self=6)

// d_out layout (floats)
#define OUT0_OFF   0u        // output  [8][512][256]
#define INTERP_OFF 1048576u  // interp  [3][4096]
#define SYM_OFF    1060864u  // symbols [8][512][256]

__device__ __forceinline__ float gelu_exact(float x) {
    return 0.5f * x * (1.0f + erff(x * 0.70710678118654752f));
}

__device__ __forceinline__ ushort f2bf(float x) {
    __hip_bfloat16 h = __float2bfloat16(x);
    union { __hip_bfloat16 b; ushort u; } cv;
    cv.b = h;
    return cv.u;
}

// Branch-free classification (reference if/elif priority, applied in reverse).
__device__ __forceinline__ int rel_of(float dx, float dy) {
    int r = (fabsf(dx) < 0.3f && fabsf(dy) < 0.3f) ? 4 : 5;
    r = (dx >  0.5f) ? 3 : r;
    r = (dx < -0.5f) ? 2 : r;
    r = (dy < -0.5f) ? 1 : r;
    r = (dy >  0.5f) ? 0 : r;
    return r;
}

// ====== 64x64-tile MFMA core pieces (4 waves, each 2x2 of 16x16x32) =======
// LDS [chunk(k/8)][row] ushort8. Fragments (m89/m91 verified):
// A: m=lane&15, k=quad*8+j ; B: n=lane&15 ; C/D: col=lane&15, row=quad*4+reg.
#define TILE_IDS()                                             \
    const int lane = tid & 63, w = tid >> 6;                   \
    const int wm = w >> 1, wn = w & 1;                         \
    const int quad = lane >> 4, l15 = lane & 15;               \
    const int sm = tid >> 2, sq = tid & 3;

#define MFMA_STEP()                                                          \
    {                                                                        \
        short8 af[2], bfr[2];                                                \
        _Pragma("unroll")                                                    \
        for (int mt = 0; mt < 2; mt++)                                       \
            af[mt] = *(const short8*)&Als[(quad * 64 + wm * 32 + mt * 16 + l15) * 8]; \
        _Pragma("unroll")                                                    \
        for (int nt = 0; nt < 2; nt++)                                       \
            bfr[nt] = *(const short8*)&Bls[(quad * 64 + wn * 32 + nt * 16 + l15) * 8]; \
        _Pragma("unroll")                                                    \
        for (int mt = 0; mt < 2; mt++)                                       \
            _Pragma("unroll")                                                \
            for (int nt = 0; nt < 2; nt++)                                   \
                acc[mt][nt] = __builtin_amdgcn_mfma_f32_16x16x32_bf16(       \
                    af[mt], bfr[nt], acc[mt][nt], 0, 0, 0);                  \
    }

#define ACC_INIT()                                             \
    f32x4 acc[2][2];                                           \
    _Pragma("unroll") for (int mt = 0; mt < 2; mt++)           \
    _Pragma("unroll") for (int nt = 0; nt < 2; nt++)           \
        acc[mt][nt] = (f32x4){0.f, 0.f, 0.f, 0.f};

// ---------------------------------------------------------------- prep ----
__global__ __launch_bounds__(256) void prep_kernel(
    const float* __restrict__ relW, const float* __restrict__ h1W,
    const float* __restrict__ outW, const float* __restrict__ h1b,
    const float* __restrict__ outb, const float* __restrict__ h2b,
    ushort* __restrict__ WcT, ushort* __restrict__ WbT,
    float* __restrict__ bbig, float* __restrict__ outI)
{
    int idx = blockIdx.x * 256 + threadIdx.x;    // grid 1536 -> 393216
    {
        int e = idx / 1536, k = idx - e * 1536;
        int r = k >> 8, d = k & 255;
        WcT[idx] = f2bf(relW[(r * DD + d) * DD + e]);
    }
    if (idx < 262144) {
        int c = idx >> 8, d = idx & 255;
        float v;
        if (c < 768) { int r = c >> 8, e = c & 255; v = h1W[(r * DD + d) * DD + e]; }
        else         { v = outW[d * DD + (c - 768)]; }
        WbT[idx] = f2bf(v);
    }
    if (idx < 3 * BNT) outI[idx] = h2b[idx >> 12];
    if (idx < 1024) bbig[idx] = (idx < 768) ? h1b[idx] : outb[idx - 768];
}

// -------------------------------------------------------------- gather ----
// One block per (b,n) row: symOut = s0 (fp32, aggregation base in d_out) and
// s0b = bf16 row-major copy (gemmT B operand).
__global__ __launch_bounds__(256) void gather_kernel(
    const int* __restrict__ ids, const float* __restrict__ symt,
    const float* __restrict__ layt, float* __restrict__ symOut,
    ushort* __restrict__ s0b)
{
    int row = blockIdx.x, c = threadIdx.x;
    int id = ids[row];
    float v = symt[id * DD + c] + layt[id * DD + c];
    symOut[(size_t)row * DD + c] = v;
    s0b[(size_t)row * DD + c] = f2bf(v);
}

// -------------------------------------------------------------- classify --
// Grid 512: b = blk>>6, j0 = (blk&63)*8. Each pair classified once;
// u8 codes rel[b][j][i] (self=6).
__global__ __launch_bounds__(256) void classify_kernel(
    const float* __restrict__ positions, unsigned char* __restrict__ rel)
{
    int b = blockIdx.x >> 6;
    int j0 = (blockIdx.x & 63) << 3;
    int tid = threadIdx.x;
    int jl = tid >> 5, sub = tid & 31;     // 8 j's x 32 workers x 16 i's
    __shared__ float px[NN], py[NN];
    for (int i = tid; i < NN; i += 256) {
        float2 p = ((const float2*)positions)[b * NN + i];
        px[i] = p.x; py[i] = p.y;
    }
    __syncthreads();
    int j = j0 + jl;
    float xj = px[j], yj = py[j];
    union { unsigned char u8[16]; uint4 v; } codes;
#pragma unroll
    for (int t = 0; t < 16; t++) {
        int i = sub * 16 + t;
        int r = rel_of(xj - px[i], yj - py[i]);
        r = (i == j) ? 6 : r;
        codes.u8[t] = (unsigned char)r;
    }
    *(uint4*)&rel[((size_t)(b * NN + j)) * NN + sub * 16] = codes.v;
}

// ----------------------------------------------------------------- gemmT --
// TT[b][e][r*512+i] = sum_d relW[r][d][e]*s0[b][i][d] + relb[r][e]
// A = WcT rows (e within r-slice), B = s0b rows. Grid (8 it, 24 rm, 8 b).
__global__ __launch_bounds__(256) void gemmT_kernel(
    const ushort* __restrict__ WcT, const ushort* __restrict__ s0b,
    const float* __restrict__ relb, ushort* __restrict__ TT)
{
    __shared__ ushort Als[2048], Bls[2048];
    int tid = threadIdx.x;
    int b = blockIdx.z;
    int rowM0 = blockIdx.y * 64;           // in [0,1536): r*256+e
    int col0 = blockIdx.x * 64;            // i tile
    int r = rowM0 >> 8, e0 = rowM0 & 255;
    TILE_IDS();
    ACC_INIT();
    const ushort* gA = WcT + (size_t)(e0 + sm) * 1536 + r * 256 + sq * 8;
    const ushort* gB = s0b + ((size_t)(b * NN) + col0 + sm) * DD + sq * 8;

    for (int k0 = 0; k0 < DD; k0 += 32) {
        uint4 av = *(const uint4*)(gA + k0);
        uint4 bv = *(const uint4*)(gB + k0);
        __syncthreads();
        *(uint4*)&Als[(sq * 64 + sm) * 8] = av;
        *(uint4*)&Bls[(sq * 64 + sm) * 8] = bv;
        __syncthreads();
        MFMA_STEP();
    }
#pragma unroll
    for (int mt = 0; mt < 2; mt++)
#pragma unroll
        for (int nt = 0; nt < 2; nt++)
#pragma unroll
            for (int v = 0; v < 4; v++) {
                int e = e0 + wm * 32 + mt * 16 + quad * 4 + v;
                int i = col0 + wn * 32 + nt * 16 + l15;
                TT[((size_t)(b * DD) + e) * 3072 + r * 512 + i] =
                    f2bf(acc[mt][nt][v] + relb[r * DD + e]);
            }
}

// ------------------------------------------------------------- agg gemm ---
// symOut[b*512+j][e] += sum_{r,i} 1[rel(i,j)=r] * TT[b][e][r*512+i]
// A one-hot generated from u8 codes; 3 K-slices (r-pairs, K=1024 each),
// grid (4 et, 8 jt, 24 b*rg) = 768 blocks. atomicAdd into symOut (= s0 base).
__global__ __launch_bounds__(256) void agg_gemm(
    const unsigned char* __restrict__ rel, const ushort* __restrict__ TT,
    float* __restrict__ symOut)
{
    __shared__ ushort Als[2048], Bls[2048];
    int tid = threadIdx.x;
    int z = blockIdx.z, b = z >> 2, rg = z & 3;   // rg: 3 used of 4? no-
    // grid z = 24 = b*3+rg
    b = z / 3; rg = z - b * 3;
    int row0 = blockIdx.y * 64, col0 = blockIdx.x * 64;
    TILE_IDS();
    ACC_INIT();
    const unsigned char* gC = rel + ((size_t)(b * NN + row0 + sm)) * NN;
    const ushort* gB = TT + ((size_t)(b * DD) + col0 + sm) * 3072 + rg * 1024 + sq * 8;

    for (int k0 = 0; k0 < 1024; k0 += 32) {
        int kk = k0 + sq * 8;                 // within slice
        int r = 2 * rg + (k0 >> 9);           // wave-uniform
        int i0 = (rg * 1024 + kk) & 511;
        uint2 cw = *(const uint2*)(gC + i0);
        uint4 bv = *(const uint4*)(gB + k0);
        union alignas(16) { ushort u[8]; uint4 v; } am;
#pragma unroll
        for (int t = 0; t < 8; t++) {
            unsigned int word = (t < 4) ? cw.x : cw.y;
            unsigned int code = (word >> (8 * (t & 3))) & 255u;
            am.u[t] = (code == (unsigned)r) ? 0x3F80 : 0;
        }
        __syncthreads();
        *(uint4*)&Als[(sq * 64 + sm) * 8] = am.v;
        *(uint4*)&Bls[(sq * 64 + sm) * 8] = bv;
        __syncthreads();
        MFMA_STEP();
    }
#pragma unroll
    for (int mt = 0; mt < 2; mt++)
#pragma unroll
        for (int nt = 0; nt < 2; nt++)
#pragma unroll
            for (int v = 0; v < 4; v++) {
                int j = row0 + wm * 32 + mt * 16 + quad * 4 + v;
                int e = col0 + wn * 32 + nt * 16 + l15;
                atomicAdd(&symOut[((size_t)(b * NN) + j) * DD + e], acc[mt][nt][v]);
            }
}

// ----------------------------------------------------------------- gemm2 --
// symOut(fp32, bf16 at staging) @ Wbig^T. Col tiles <768: gelu + fused
// interp reduce (atomicAdd into outI pre-loaded with h2b). Else: out0.
__global__ __launch_bounds__(256) void gemm2_kernel(
    const float* __restrict__ symOut, const ushort* __restrict__ WbT,
    const float* __restrict__ bbig, const float* __restrict__ h2W,
    float* __restrict__ out0, float* __restrict__ outI)
{
    __shared__ ushort Als[2048], Bls[2048];
    int tid = threadIdx.x;
    int row0 = blockIdx.y * 64, col0 = blockIdx.x * 64;
    TILE_IDS();
    ACC_INIT();
    const float*  gA = symOut + (size_t)(row0 + sm) * DD + sq * 8;
    const ushort* gB = WbT    + (size_t)(col0 + sm) * DD + sq * 8;

    for (int k0 = 0; k0 < DD; k0 += 32) {
        union alignas(16) { float f[8]; float4 v4[2]; } af32;
        af32.v4[0] = *(const float4*)(gA + k0);
        af32.v4[1] = *(const float4*)(gA + k0 + 4);
        uint4 bv = *(const uint4*)(gB + k0);
        union alignas(16) { ushort u[8]; uint4 v; } am;
#pragma unroll
        for (int t = 0; t < 8; t++) am.u[t] = f2bf(af32.f[t]);
        __syncthreads();
        *(uint4*)&Als[(sq * 64 + sm) * 8] = am.v;
        *(uint4*)&Bls[(sq * 64 + sm) * 8] = bv;
        __syncthreads();
        MFMA_STEP();
    }
    if (col0 >= 768) {
#pragma unroll
        for (int nt = 0; nt < 2; nt++) {
            int c = col0 + wn * 32 + nt * 16 + l15;
            float bb = bbig[c];
#pragma unroll
            for (int mt = 0; mt < 2; mt++)
#pragma unroll
                for (int v = 0; v < 4; v++) {
                    int row = row0 + wm * 32 + mt * 16 + quad * 4 + v;
                    out0[(size_t)row * DD + (c - 768)] = acc[mt][nt][v] + bb;
                }
        }
    } else {
        int head = col0 >> 8;
        float part[2][4];
#pragma unroll
        for (int mt = 0; mt < 2; mt++)
#pragma unroll
            for (int v = 0; v < 4; v++) part[mt][v] = 0.f;
#pragma unroll
        for (int nt = 0; nt < 2; nt++) {
            int c = col0 + wn * 32 + nt * 16 + l15;
            float bb = bbig[c];
            float w2 = h2W[c];
#pragma unroll
            for (int mt = 0; mt < 2; mt++)
#pragma unroll
                for (int v = 0; v < 4; v++)
                    part[mt][v] += gelu_exact(acc[mt][nt][v] + bb) * w2;
        }
#pragma unroll
        for (int mt = 0; mt < 2; mt++)
#pragma unroll
            for (int v = 0; v < 4; v++) {
                float p = part[mt][v];
                p += __shfl_xor(p, 1); p += __shfl_xor(p, 2);
                p += __shfl_xor(p, 4); p += __shfl_xor(p, 8);
                if (l15 == 0) {
                    int row = row0 + wm * 32 + mt * 16 + quad * 4 + v;
                    atomicAdd(&outI[head * BNT + row], p);
                }
            }
    }
}

// ---------------------------------------------------------------- launch --
extern "C" void kernel_launch(void* const* d_in, const int* in_sizes, int n_in,
                              void* d_out, int out_size, void* d_ws, size_t ws_size,
                              hipStream_t stream)
{
    const int*   ids  = (const int*)d_in[0];
    const float* pos  = (const float*)d_in[1];
    const float* symt = (const float*)d_in[2];
    const float* layt = (const float*)d_in[3];
    const float* relW = (const float*)d_in[4];
    const float* relb = (const float*)d_in[5];
    const float* h1W  = (const float*)d_in[6];
    const float* h1b  = (const float*)d_in[7];
    const float* h2W  = (const float*)d_in[8];
    const float* h2b  = (const float*)d_in[9];
    const float* outW = (const float*)d_in[10];
    const float* outb = (const float*)d_in[11];
    float* out = (float*)d_out;
    float* ws  = (float*)d_ws;

    ushort* s0b  = (ushort*)(ws + OFF_S0B);
    ushort* TT   = (ushort*)(ws + OFF_TT);
    ushort* WcT  = (ushort*)(ws + OFF_WCT);
    ushort* WbT  = (ushort*)(ws + OFF_WBT);
    float*  bbig = ws + OFF_BB;
    unsigned char* rel = (unsigned char*)(ws + OFF_REL);

    prep_kernel<<<1536, 256, 0, stream>>>(relW, h1W, outW, h1b, outb, h2b,
                                          WcT, WbT, bbig, out + INTERP_OFF);
    gather_kernel<<<4096, 256, 0, stream>>>(ids, symt, layt, out + SYM_OFF, s0b);
    classify_kernel<<<512, 256, 0, stream>>>(pos, rel);
    gemmT_kernel<<<dim3(8, 24, 8), 256, 0, stream>>>(WcT, s0b, relb, TT);
    agg_gemm<<<dim3(4, 8, 24), 256, 0, stream>>>(rel, TT, out + SYM_OFF);
    gemm2_kernel<<<dim3(16, 64), 256, 0, stream>>>(out + SYM_OFF, WbT,
                                                   bbig, h2W,
                                                   out + OUT0_OFF, out + INTERP_OFF);
}

// Round 10
// 139.775 us; speedup vs baseline: 1.6437x; 1.0280x over previous
//
#include <hip/hip_runtime.h>
#include <hip/hip_bf16.h>
#include <math.h>

#define BB 8
#define NN 512
#define DD 256
#define BNT 4096   // B*N

typedef __attribute__((ext_vector_type(8))) short short8;
typedef __attribute__((ext_vector_type(4))) float f32x4;

// Workspace layout (float offsets). ~18 MB.
#define OFF_S0B   0u          // bf16 [4096][256]      s0 row-major (gemmT B)
#define OFF_TT    524288u     // bf16 [8][256][3072]   TT[b][e][r*512+i] = T_r[i][e]+relb_r[e]
#define OFF_WCT   6815744u    // bf16 [256][1536]      WcT[e][r*256+d] = relW[r][d][e]
#define OFF_WBT   7012352u    // bf16 [1024][256]      Wbig^T (c rows, k=d)
#define OFF_BB    7143424u    // fp32 [1024]           h1b|outb
#define OFF_REL   7144448u    // u8   [8][512][512]    relation codes (self=6)

// d_out layout (floats)
#define OUT0_OFF   0u        // output  [8][512][256]
#define INTERP_OFF 1048576u  // interp  [3][4096]
#define SYM_OFF    1060864u  // symbols [8][512][256]

__device__ __forceinline__ float gelu_exact(float x) {
    return 0.5f * x * (1.0f + erff(x * 0.70710678118654752f));
}

__device__ __forceinline__ ushort f2bf(float x) {
    __hip_bfloat16 h = __float2bfloat16(x);
    union { __hip_bfloat16 b; ushort u; } cv;
    cv.b = h;
    return cv.u;
}

// Branch-free classification (reference if/elif priority, applied in reverse).
__device__ __forceinline__ int rel_of(float dx, float dy) {
    int r = (fabsf(dx) < 0.3f && fabsf(dy) < 0.3f) ? 4 : 5;
    r = (dx >  0.5f) ? 3 : r;
    r = (dx < -0.5f) ? 2 : r;
    r = (dy < -0.5f) ? 1 : r;
    r = (dy >  0.5f) ? 0 : r;
    return r;
}

// ====== 64x64-tile MFMA core (4 waves 2x2), double-buffered LDS ===========
// LDS [chunk(k/8)][row] ushort8 (conflict-free b128 reads). Fragments
// (m89/m91 verified): A: m=lane&15,k=quad*8+j; B: n=lane&15;
// C/D: col=lane&15, row=quad*4+reg.
#define TILE_IDS()                                             \
    const int lane = tid & 63, w = tid >> 6;                   \
    const int wm = w >> 1, wn = w & 1;                         \
    const int quad = lane >> 4, l15 = lane & 15;               \
    const int sm = tid >> 2, sq = tid & 3;

#define MFMA_STEP(Abuf, Bbuf)                                                \
    {                                                                        \
        short8 af[2], bfr[2];                                                \
        _Pragma("unroll")                                                    \
        for (int mt = 0; mt < 2; mt++)                                       \
            af[mt] = *(const short8*)&(Abuf)[(quad * 64 + wm * 32 + mt * 16 + l15) * 8]; \
        _Pragma("unroll")                                                    \
        for (int nt = 0; nt < 2; nt++)                                       \
            bfr[nt] = *(const short8*)&(Bbuf)[(quad * 64 + wn * 32 + nt * 16 + l15) * 8]; \
        _Pragma("unroll")                                                    \
        for (int mt = 0; mt < 2; mt++)                                       \
            _Pragma("unroll")                                                \
            for (int nt = 0; nt < 2; nt++)                                   \
                acc[mt][nt] = __builtin_amdgcn_mfma_f32_16x16x32_bf16(       \
                    af[mt], bfr[nt], acc[mt][nt], 0, 0, 0);                  \
    }

#define ACC_INIT()                                             \
    f32x4 acc[2][2];                                           \
    _Pragma("unroll") for (int mt = 0; mt < 2; mt++)           \
    _Pragma("unroll") for (int nt = 0; nt < 2; nt++)           \
        acc[mt][nt] = (f32x4){0.f, 0.f, 0.f, 0.f};

// ---------------------------------------------------------------- front ---
// Fused prep (blocks 0..1535) + gather (1536..5631) + classify (5632..6143).
// The three parts are mutually independent; fusing overlaps VALU-heavy
// classification with memory-heavy gather and removes 2 stream barriers.
__global__ __launch_bounds__(256) void front_kernel(
    const int* __restrict__ ids, const float* __restrict__ positions,
    const float* __restrict__ symt, const float* __restrict__ layt,
    const float* __restrict__ relW, const float* __restrict__ h1W,
    const float* __restrict__ outW, const float* __restrict__ h1b,
    const float* __restrict__ outb, const float* __restrict__ h2b,
    ushort* __restrict__ WcT, ushort* __restrict__ WbT,
    float* __restrict__ bbig, float* __restrict__ outI,
    float* __restrict__ symOut, ushort* __restrict__ s0b,
    unsigned char* __restrict__ rel)
{
    __shared__ float px[NN], py[NN];
    int blk = blockIdx.x, tid = threadIdx.x;
    if (blk < 1536) {
        int idx = blk * 256 + tid;               // 393216
        {
            int e = idx / 1536, k = idx - e * 1536;
            int r = k >> 8, d = k & 255;
            WcT[idx] = f2bf(relW[(r * DD + d) * DD + e]);
        }
        if (idx < 262144) {
            int c = idx >> 8, d = idx & 255;
            float v;
            if (c < 768) { int r = c >> 8, e = c & 255; v = h1W[(r * DD + d) * DD + e]; }
            else         { v = outW[d * DD + (c - 768)]; }
            WbT[idx] = f2bf(v);
        }
        if (idx < 3 * BNT) outI[idx] = h2b[idx >> 12];
        if (idx < 1024) bbig[idx] = (idx < 768) ? h1b[idx] : outb[idx - 768];
    } else if (blk < 5632) {
        int row = blk - 1536;                    // [0,4096)
        int id = ids[row];
        float v = symt[id * DD + tid] + layt[id * DD + tid];
        symOut[(size_t)row * DD + tid] = v;
        s0b[(size_t)row * DD + tid] = f2bf(v);
    } else {
        int blk2 = blk - 5632;                   // [0,512)
        int b = blk2 >> 6;
        int j0 = (blk2 & 63) << 3;
        int jl = tid >> 5, sub = tid & 31;       // 8 j's x 32 workers x 16 i's
        for (int i = tid; i < NN; i += 256) {
            float2 p = ((const float2*)positions)[b * NN + i];
            px[i] = p.x; py[i] = p.y;
        }
        __syncthreads();
        int j = j0 + jl;
        float xj = px[j], yj = py[j];
        union { unsigned char u8[16]; uint4 v; } codes;
#pragma unroll
        for (int t = 0; t < 16; t++) {
            int i = sub * 16 + t;
            int r = rel_of(xj - px[i], yj - py[i]);
            r = (i == j) ? 6 : r;
            codes.u8[t] = (unsigned char)r;
        }
        *(uint4*)&rel[((size_t)(b * NN + j)) * NN + sub * 16] = codes.v;
    }
}

// ----------------------------------------------------------------- gemmT --
// TT[b][e][r*512+i] = sum_d relW[r][d][e]*s0[b][i][d] + relb[r][e]
// Double-buffered; grid (8 it, 24 rm, 8 b) = 1536 blocks.
__global__ __launch_bounds__(256) void gemmT_kernel(
    const ushort* __restrict__ WcT, const ushort* __restrict__ s0b,
    const float* __restrict__ relb, ushort* __restrict__ TT)
{
    __shared__ ushort Als[2][2048], Bls[2][2048];
    int tid = threadIdx.x;
    int b = blockIdx.z;
    int rowM0 = blockIdx.y * 64;           // in [0,1536): r*256+e
    int col0 = blockIdx.x * 64;            // i tile
    int r = rowM0 >> 8, e0 = rowM0 & 255;
    TILE_IDS();
    ACC_INIT();
    const ushort* gA = WcT + (size_t)(e0 + sm) * 1536 + r * 256 + sq * 8;
    const ushort* gB = s0b + ((size_t)(b * NN) + col0 + sm) * DD + sq * 8;
    const int lo = (sq * 64 + sm) * 8;

    *(uint4*)&Als[0][lo] = *(const uint4*)gA;
    *(uint4*)&Bls[0][lo] = *(const uint4*)gB;
#pragma unroll
    for (int i = 0; i < 8; i++) {
        __syncthreads();
        uint4 av2, bv2;
        if (i < 7) {
            av2 = *(const uint4*)(gA + (i + 1) * 32);
            bv2 = *(const uint4*)(gB + (i + 1) * 32);
        }
        MFMA_STEP(Als[i & 1], Bls[i & 1]);
        if (i < 7) {
            *(uint4*)&Als[(i + 1) & 1][lo] = av2;
            *(uint4*)&Bls[(i + 1) & 1][lo] = bv2;
        }
    }
#pragma unroll
    for (int mt = 0; mt < 2; mt++)
#pragma unroll
        for (int nt = 0; nt < 2; nt++)
#pragma unroll
            for (int v = 0; v < 4; v++) {
                int e = e0 + wm * 32 + mt * 16 + quad * 4 + v;
                int i = col0 + wn * 32 + nt * 16 + l15;
                TT[((size_t)(b * DD) + e) * 3072 + r * 512 + i] =
                    f2bf(acc[mt][nt][v] + relb[r * DD + e]);
            }
}

// ------------------------------------------------------------- agg gemm ---
// symOut[b*512+j][e] += sum_{r,i} 1[rel(i,j)=r] * TT[b][e][r*512+i]
// One-hot A from u8 codes; 3 K-slices (r-pairs, K=1024), grid (4,8,24).
// Double-buffered; atomicAdd into symOut (= s0 base from front).
__global__ __launch_bounds__(256) void agg_gemm(
    const unsigned char* __restrict__ rel, const ushort* __restrict__ TT,
    float* __restrict__ symOut)
{
    __shared__ ushort Als[2][2048], Bls[2][2048];
    int tid = threadIdx.x;
    int z = blockIdx.z;
    int b = z / 3, rg = z - b * 3;
    int row0 = blockIdx.y * 64, col0 = blockIdx.x * 64;
    TILE_IDS();
    ACC_INIT();
    const unsigned char* gC = rel + ((size_t)(b * NN + row0 + sm)) * NN;
    const ushort* gB = TT + ((size_t)(b * DD) + col0 + sm) * 3072 + rg * 1024 + sq * 8;
    const int lo = (sq * 64 + sm) * 8;

#define AGG_LOADS(i, cw, bv)                                        \
    cw = *(const uint2*)(gC + (((i) * 32 + sq * 8) & 511));         \
    bv = *(const uint4*)(gB + (i) * 32);

#define AGG_STAGE(i, cw, bv, buf)                                   \
    {                                                               \
        int rr_ = 2 * rg + (((i) * 32) >> 9);                       \
        union alignas(16) { ushort u[8]; uint4 v; } am;             \
        _Pragma("unroll")                                           \
        for (int t = 0; t < 8; t++) {                               \
            unsigned int word = (t < 4) ? cw.x : cw.y;              \
            unsigned int code = (word >> (8 * (t & 3))) & 255u;     \
            am.u[t] = (code == (unsigned)rr_) ? 0x3F80 : 0;         \
        }                                                           \
        *(uint4*)&Als[buf][lo] = am.v;                              \
        *(uint4*)&Bls[buf][lo] = bv;                                \
    }

    uint2 cw0; uint4 bv0;
    AGG_LOADS(0, cw0, bv0);
    AGG_STAGE(0, cw0, bv0, 0);
    for (int i = 0; i < 32; i++) {
        __syncthreads();
        uint2 cw2; uint4 bv2;
        if (i < 31) { AGG_LOADS(i + 1, cw2, bv2); }
        MFMA_STEP(Als[i & 1], Bls[i & 1]);
        if (i < 31) { AGG_STAGE(i + 1, cw2, bv2, (i + 1) & 1); }
    }
#undef AGG_LOADS
#undef AGG_STAGE
#pragma unroll
    for (int mt = 0; mt < 2; mt++)
#pragma unroll
        for (int nt = 0; nt < 2; nt++)
#pragma unroll
            for (int v = 0; v < 4; v++) {
                int j = row0 + wm * 32 + mt * 16 + quad * 4 + v;
                int e = col0 + wn * 32 + nt * 16 + l15;
                atomicAdd(&symOut[((size_t)(b * NN) + j) * DD + e], acc[mt][nt][v]);
            }
}

// ----------------------------------------------------------------- gemm2 --
// symOut(fp32, bf16 at staging) @ Wbig^T. Col tiles <768: gelu + fused
// interp reduce (atomicAdd into outI pre-loaded with h2b). Else: out0.
__global__ __launch_bounds__(256) void gemm2_kernel(
    const float* __restrict__ symOut, const ushort* __restrict__ WbT,
    const float* __restrict__ bbig, const float* __restrict__ h2W,
    float* __restrict__ out0, float* __restrict__ outI)
{
    __shared__ ushort Als[2][2048], Bls[2][2048];
    int tid = threadIdx.x;
    int row0 = blockIdx.y * 64, col0 = blockIdx.x * 64;
    TILE_IDS();
    ACC_INIT();
    const float*  gA = symOut + (size_t)(row0 + sm) * DD + sq * 8;
    const ushort* gB = WbT    + (size_t)(col0 + sm) * DD + sq * 8;
    const int lo = (sq * 64 + sm) * 8;

#define G2_LOADS(i, a0, a1, bv)                                     \
    a0 = *(const float4*)(gA + (i) * 32);                           \
    a1 = *(const float4*)(gA + (i) * 32 + 4);                       \
    bv = *(const uint4*)(gB + (i) * 32);

#define G2_STAGE(a0, a1, bv, buf)                                   \
    {                                                               \
        union alignas(16) { ushort u[8]; uint4 v; } am;             \
        am.u[0] = f2bf(a0.x); am.u[1] = f2bf(a0.y);                 \
        am.u[2] = f2bf(a0.z); am.u[3] = f2bf(a0.w);                 \
        am.u[4] = f2bf(a1.x); am.u[5] = f2bf(a1.y);                 \
        am.u[6] = f2bf(a1.z); am.u[7] = f2bf(a1.w);                 \
        *(uint4*)&Als[buf][lo] = am.v;                              \
        *(uint4*)&Bls[buf][lo] = bv;                                \
    }

    float4 a0, a1; uint4 bv;
    G2_LOADS(0, a0, a1, bv);
    G2_STAGE(a0, a1, bv, 0);
#pragma unroll
    for (int i = 0; i < 8; i++) {
        __syncthreads();
        float4 a0n, a1n; uint4 bvn;
        if (i < 7) { G2_LOADS(i + 1, a0n, a1n, bvn); }
        MFMA_STEP(Als[i & 1], Bls[i & 1]);
        if (i < 7) { G2_STAGE(a0n, a1n, bvn, (i + 1) & 1); }
    }
#undef G2_LOADS
#undef G2_STAGE
    if (col0 >= 768) {
#pragma unroll
        for (int nt = 0; nt < 2; nt++) {
            int c = col0 + wn * 32 + nt * 16 + l15;
            float bb = bbig[c];
#pragma unroll
            for (int mt = 0; mt < 2; mt++)
#pragma unroll
                for (int v = 0; v < 4; v++) {
                    int row = row0 + wm * 32 + mt * 16 + quad * 4 + v;
                    out0[(size_t)row * DD + (c - 768)] = acc[mt][nt][v] + bb;
                }
        }
    } else {
        int head = col0 >> 8;
        float part[2][4];
#pragma unroll
        for (int mt = 0; mt < 2; mt++)
#pragma unroll
            for (int v = 0; v < 4; v++) part[mt][v] = 0.f;
#pragma unroll
        for (int nt = 0; nt < 2; nt++) {
            int c = col0 + wn * 32 + nt * 16 + l15;
            float bb = bbig[c];
            float w2 = h2W[c];
#pragma unroll
            for (int mt = 0; mt < 2; mt++)
#pragma unroll
                for (int v = 0; v < 4; v++)
                    part[mt][v] += gelu_exact(acc[mt][nt][v] + bb) * w2;
        }
#pragma unroll
        for (int mt = 0; mt < 2; mt++)
#pragma unroll
            for (int v = 0; v < 4; v++) {
                float p = part[mt][v];
                p += __shfl_xor(p, 1); p += __shfl_xor(p, 2);
                p += __shfl_xor(p, 4); p += __shfl_xor(p, 8);
                if (l15 == 0) {
                    int row = row0 + wm * 32 + mt * 16 + quad * 4 + v;
                    atomicAdd(&outI[head * BNT + row], p);
                }
            }
    }
}

// ---------------------------------------------------------------- launch --
extern "C" void kernel_launch(void* const* d_in, const int* in_sizes, int n_in,
                              void* d_out, int out_size, void* d_ws, size_t ws_size,
                              hipStream_t stream)
{
    const int*   ids  = (const int*)d_in[0];
    const float* pos  = (const float*)d_in[1];
    const float* symt = (const float*)d_in[2];
    const float* layt = (const float*)d_in[3];
    const float* relW = (const float*)d_in[4];
    const float* relb = (const float*)d_in[5];
    const float* h1W  = (const float*)d_in[6];
    const float* h1b  = (const float*)d_in[7];
    const float* h2W  = (const float*)d_in[8];
    const float* h2b  = (const float*)d_in[9];
    const float* outW = (const float*)d_in[10];
    const float* outb = (const float*)d_in[11];
    float* out = (float*)d_out;
    float* ws  = (float*)d_ws;

    ushort* s0b  = (ushort*)(ws + OFF_S0B);
    ushort* TT   = (ushort*)(ws + OFF_TT);
    ushort* WcT  = (ushort*)(ws + OFF_WCT);
    ushort* WbT  = (ushort*)(ws + OFF_WBT);
    float*  bbig = ws + OFF_BB;
    unsigned char* rel = (unsigned char*)(ws + OFF_REL);

    front_kernel<<<6144, 256, 0, stream>>>(ids, pos, symt, layt, relW, h1W, outW,
                                           h1b, outb, h2b, WcT, WbT, bbig,
                                           out + INTERP_OFF, out + SYM_OFF, s0b, rel);
    gemmT_kernel<<<dim3(8, 24, 8), 256, 0, stream>>>(WcT, s0b, relb, TT);
    agg_gemm<<<dim3(4, 8, 24), 256, 0, stream>>>(rel, TT, out + SYM_OFF);
    gemm2_kernel<<<dim3(16, 64), 256, 0, stream>>>(out + SYM_OFF, WbT,
                                                   bbig, h2W,
                                                   out + OUT0_OFF, out + INTERP_OFF);
}